// Round 7
// baseline (349.432 us; speedup 1.0000x reference)
//
#include <hip/hip_runtime.h>

typedef unsigned short u16;
typedef unsigned int u32;
typedef __attribute__((ext_vector_type(8))) short short8;
typedef __attribute__((ext_vector_type(8))) __bf16 bf16x8;
typedef __attribute__((ext_vector_type(4))) float f32x4;
typedef __attribute__((ext_vector_type(2))) u32 u32x2;

// ---------- bf16 <-> f32 (raw, RNE) ----------
__device__ __forceinline__ float bf2f(u16 u) { return __uint_as_float(((u32)u) << 16); }
__device__ __forceinline__ u16 f2bf(float f) {
  u32 u = __float_as_uint(f);
  u = (u + 0x7fffu + ((u >> 16) & 1u)) >> 16;
  return (u16)u;
}

// ---------- fast 2^x ----------
__device__ __forceinline__ float EXP2(float x) {
#if __has_builtin(__builtin_amdgcn_exp2f)
  return __builtin_amdgcn_exp2f(x);
#else
  return exp2f(x);
#endif
}

// ---------- packed f32x2 -> bf16x2 (RNE), gfx950 v_cvt_pk_bf16_f32 ----------
__device__ __forceinline__ u32 CVTPK(float lo, float hi) {
  u32 r;
  asm("v_cvt_pk_bf16_f32 %0, %1, %2" : "=v"(r) : "v"(lo), "v"(hi));
  return r;
}

// ---------- MFMA wrapper ----------
template <typename V>
__device__ __forceinline__ auto mfma_try(V a, V b, f32x4 c, int)
    -> decltype(__builtin_amdgcn_mfma_f32_16x16x32_bf16(a, b, c, 0, 0, 0)) {
  return __builtin_amdgcn_mfma_f32_16x16x32_bf16(a, b, c, 0, 0, 0);
}
template <typename V>
__device__ __forceinline__ f32x4 mfma_try(V a, V b, f32x4 c, long) {
  return __builtin_amdgcn_mfma_f32_16x16x32_bf16(
      __builtin_bit_cast(bf16x8, a), __builtin_bit_cast(bf16x8, b), c, 0, 0, 0);
}
__device__ __forceinline__ f32x4 MFMA(short8 a, short8 b, f32x4 c) {
  return mfma_try(a, b, c, 0);
}

// ---------- async global->LDS, 16B per lane (GEMM only) ----------
#define GLOAD16(gsrc, ldst)                                                  \
  __builtin_amdgcn_global_load_lds(                                          \
      (const __attribute__((address_space(1))) void*)(gsrc),                 \
      (__attribute__((address_space(3))) void*)(ldst), 16, 0, 0)

// Problem constants
#define SQ 2048
#define NH 16
#define DH 64
#define DMODEL 1024

// =====================================================================
// dtype detector: flag=1 if inputs are float32, 0 if bf16.
// =====================================================================
__global__ void detect_dtype(const u16* __restrict__ q, int* __restrict__ flag) {
  __shared__ int cnt;
  if (threadIdx.x == 0) cnt = 0;
  __syncthreads();
  const int k = threadIdx.x * 16384 + 128;
  const u16 u = q[2 * k];
  const int e = (u >> 7) & 0xFF;
  if (e >= 96 && e <= 143) atomicAdd(&cnt, 1);
  __syncthreads();
  if (threadIdx.x == 0) *flag = (cnt < 128) ? 1 : 0;
}

// ---------- conversion helpers ----------
__device__ __forceinline__ short8 cvt8_f32(const float* s) {
  f32x4 a = *(const f32x4*)s;
  f32x4 b = *(const f32x4*)(s + 4);
  short8 o;
#pragma unroll
  for (int j = 0; j < 4; ++j) o[j] = (short)f2bf(a[j]);
#pragma unroll
  for (int j = 0; j < 4; ++j) o[4 + j] = (short)f2bf(b[j]);
  return o;
}

__global__ void cvt_tensor(const void* __restrict__ src, u16* __restrict__ dst,
                           int n8, const int* __restrict__ flag) {
  const bool isf32 = (*flag != 0);
  int i = blockIdx.x * blockDim.x + threadIdx.x;
  const int stride = gridDim.x * blockDim.x;
  if (isf32) {
    const float* s = (const float*)src;
    for (; i < n8; i += stride) *(short8*)(dst + i * 8) = cvt8_f32(s + i * 8);
  } else {
    const short8* s = (const short8*)src;
    for (; i < n8; i += stride) *(short8*)(dst + i * 8) = s[i];
  }
}

__global__ void cvt_w4(const void* s0, const void* s1, const void* s2, const void* s3,
                       u16* __restrict__ dst, const int* __restrict__ flag) {
  const bool isf32 = (*flag != 0);
  int i = blockIdx.x * blockDim.x + threadIdx.x;
  const int stride = gridDim.x * blockDim.x;
  for (; i < (1 << 19); i += stride) {
    const int seg = i >> 17, off = i & ((1 << 17) - 1);
    const void* s = (seg == 0) ? s0 : (seg == 1) ? s1 : (seg == 2) ? s2 : s3;
    u16* d = dst + ((long)seg << 20) + (long)off * 8;
    if (isf32) *(short8*)d = cvt8_f32((const float*)s + off * 8);
    else *(short8*)d = *((const short8*)s + off);
  }
}

__global__ void cvt_b4(const void* s0, const void* s1, const void* s2, const void* s3,
                       u16* __restrict__ dst, const int* __restrict__ flag) {
  const bool isf32 = (*flag != 0);
  int i = blockIdx.x * blockDim.x + threadIdx.x;
  if (i >= 512) return;
  const int seg = i >> 7, off = i & 127;
  const void* s = (seg == 0) ? s0 : (seg == 1) ? s1 : (seg == 2) ? s2 : s3;
  u16* d = dst + seg * 1024 + off * 8;
  if (isf32) *(short8*)d = cvt8_f32((const float*)s + off * 8);
  else *(short8*)d = *((const short8*)s + off);
}

// =====================================================================
// Fused QKV GEMM: A[8192][1024] x W[3072][1024]^T + bias[3072]
// col segment 0 -> qb heads, 1 -> kb heads, 2 -> vT transposed.
// 128x128 tile, BK=32, 256 threads.  grid 64*24 = 1536 blocks.
// =====================================================================
__global__ __launch_bounds__(256, 2) void gemm_qkv(
    const u16* __restrict__ A, const u16* __restrict__ W,
    const u16* __restrict__ bias, u16* __restrict__ qb,
    u16* __restrict__ kb, u16* __restrict__ vT) {
  __shared__ __align__(16) u16 As[128 * 32];
  __shared__ __align__(16) u16 Bs[128 * 32];
  const int tid = threadIdx.x;
  const int lane = tid & 63;
  const int wv = tid >> 6;
  const int wr = wv >> 1, wc = wv & 1;
  const int K = DMODEL;

  const int nwg = gridDim.x;                 // 1536
  const int cpx = nwg >> 3;
  const int bid = (blockIdx.x % 8) * cpx + (blockIdx.x >> 3);

  const int tm = bid / 24, tn = bid % 24;
  const int m0 = tm << 7, n0 = tn << 7;

  f32x4 acc[4][4];
#pragma unroll
  for (int i = 0; i < 4; ++i)
#pragma unroll
    for (int j = 0; j < 4; ++j)
#pragma unroll
      for (int r = 0; r < 4; ++r) acc[i][j][r] = 0.f;

  const int srow = tid >> 2;
  const int skk = (tid & 3) * 8;
  const u16* a0 = A + (long)(m0 + srow) * K + skk;
  const u16* a1 = A + (long)(m0 + 64 + srow) * K + skk;
  const u16* b0 = W + (long)(n0 + srow) * K + skk;
  const u16* b1 = W + (long)(n0 + 64 + srow) * K + skk;
  u16* lA0 = &As[tid * 8];
  u16* lA1 = &As[(256 + tid) * 8];
  u16* lB0 = &Bs[tid * 8];
  u16* lB1 = &Bs[(256 + tid) * 8];

  const int rk = 8 * (lane >> 4);
  const int rrow = lane & 15;
  const int r0 = (lane >> 4) * 4;

  for (int k0 = 0; k0 < K; k0 += 32) {
    GLOAD16(a0 + k0, lA0);
    GLOAD16(a1 + k0, lA1);
    GLOAD16(b0 + k0, lB0);
    GLOAD16(b1 + k0, lB1);
    asm volatile("s_waitcnt vmcnt(0)" ::: "memory");
    __syncthreads();
    short8 af[4], bf[4];
#pragma unroll
    for (int mi = 0; mi < 4; ++mi)
      af[mi] = *(const short8*)&As[(wr * 64 + mi * 16 + rrow) * 32 + rk];
#pragma unroll
    for (int ni = 0; ni < 4; ++ni)
      bf[ni] = *(const short8*)&Bs[(wc * 64 + ni * 16 + rrow) * 32 + rk];
#pragma unroll
    for (int mi = 0; mi < 4; ++mi)
#pragma unroll
      for (int ni = 0; ni < 4; ++ni)
        acc[mi][ni] = MFMA(af[mi], bf[ni], acc[mi][ni]);
    __syncthreads();
  }

  // epilogue with block-uniform segment routing
  const int seg = n0 >> 10;             // 0=Q, 1=K, 2=V
  const int nbase = n0 & 1023;
  u16* dst = (seg == 0) ? qb : (seg == 1) ? kb : vT;
#pragma unroll
  for (int ni = 0; ni < 4; ++ni) {
    const int col = n0 + wc * 64 + ni * 16 + rrow;
    const float bv = bf2f(bias[col]);
    const int cl = nbase + wc * 64 + ni * 16 + rrow;
    const int h = cl >> 6, dh = cl & 63;
#pragma unroll
    for (int mi = 0; mi < 4; ++mi) {
#pragma unroll
      for (int r = 0; r < 4; ++r) {
        const int row = m0 + wr * 64 + mi * 16 + r0 + r;
        const float v = acc[mi][ni][r] + bv;
        const int b = row >> 11, s = row & 2047;
        if (seg < 2) {
          dst[(((long)(b * NH + h) * SQ) + s) * DH + dh] = f2bf(v);
        } else {
          dst[(((long)(b * NH + h) * DH) + dh) * SQ + s] = f2bf(v);
        }
      }
    }
  }
}

// =====================================================================
// Wo GEMM: C[M][N] = A[M][K] * W[N][K]^T + bias[N], row-major out
// =====================================================================
__global__ __launch_bounds__(256, 2) void gemm_out(
    const u16* __restrict__ A, const u16* __restrict__ W,
    const u16* __restrict__ bias, void* __restrict__ Cv,
    const int* __restrict__ flag, int M, int N, int K) {
  __shared__ __align__(16) u16 As[128 * 32];
  __shared__ __align__(16) u16 Bs[128 * 32];
  const int tid = threadIdx.x;
  const int lane = tid & 63;
  const int wv = tid >> 6;
  const int wr = wv >> 1, wc = wv & 1;
  const bool isf32 = (*flag != 0);

  const int nwg = gridDim.x;
  const int cpx = nwg >> 3;
  const int bid = (blockIdx.x % 8) * cpx + (blockIdx.x >> 3);

  const int tiles_n = N >> 7;
  const int tm = bid / tiles_n, tn = bid % tiles_n;
  const int m0 = tm << 7, n0 = tn << 7;

  f32x4 acc[4][4];
#pragma unroll
  for (int i = 0; i < 4; ++i)
#pragma unroll
    for (int j = 0; j < 4; ++j)
#pragma unroll
      for (int r = 0; r < 4; ++r) acc[i][j][r] = 0.f;

  const int srow = tid >> 2;
  const int skk = (tid & 3) * 8;
  const u16* a0 = A + (long)(m0 + srow) * K + skk;
  const u16* a1 = A + (long)(m0 + 64 + srow) * K + skk;
  const u16* b0 = W + (long)(n0 + srow) * K + skk;
  const u16* b1 = W + (long)(n0 + 64 + srow) * K + skk;
  u16* lA0 = &As[tid * 8];
  u16* lA1 = &As[(256 + tid) * 8];
  u16* lB0 = &Bs[tid * 8];
  u16* lB1 = &Bs[(256 + tid) * 8];

  const int rk = 8 * (lane >> 4);
  const int rrow = lane & 15;
  const int r0 = (lane >> 4) * 4;

  for (int k0 = 0; k0 < K; k0 += 32) {
    GLOAD16(a0 + k0, lA0);
    GLOAD16(a1 + k0, lA1);
    GLOAD16(b0 + k0, lB0);
    GLOAD16(b1 + k0, lB1);
    asm volatile("s_waitcnt vmcnt(0)" ::: "memory");
    __syncthreads();
    short8 af[4], bf[4];
#pragma unroll
    for (int mi = 0; mi < 4; ++mi)
      af[mi] = *(const short8*)&As[(wr * 64 + mi * 16 + rrow) * 32 + rk];
#pragma unroll
    for (int ni = 0; ni < 4; ++ni)
      bf[ni] = *(const short8*)&Bs[(wc * 64 + ni * 16 + rrow) * 32 + rk];
#pragma unroll
    for (int mi = 0; mi < 4; ++mi)
#pragma unroll
      for (int ni = 0; ni < 4; ++ni)
        acc[mi][ni] = MFMA(af[mi], bf[ni], acc[mi][ni]);
    __syncthreads();
  }

#pragma unroll
  for (int ni = 0; ni < 4; ++ni) {
    const int col = n0 + wc * 64 + ni * 16 + rrow;
    const float bv = bf2f(bias[col]);
#pragma unroll
    for (int mi = 0; mi < 4; ++mi) {
#pragma unroll
      for (int r = 0; r < 4; ++r) {
        const int row = m0 + wr * 64 + mi * 16 + r0 + r;
        const float v = acc[mi][ni][r] + bv;
        const long idx = (long)row * N + col;
        if (isf32) ((float*)Cv)[idx] = v;
        else ((u16*)Cv)[idx] = f2bf(v);
      }
    }
  }
}

// =====================================================================
// Flash attention, swapped-QK^T, KVBLK=128, 2 barriers per tile.
// q,k in [BH][S][64], vT in [BH][64][S], out ctx [B][S][H][64]
// grid (S/128, BH), 256 threads = 4 waves, each wave 32 q-rows.
// PV in two 64-kv passes reusing one wave-private Ps buffer (no barrier).
// =====================================================================
#define KVB 128
#define LSTR 72    // Ks row stride (u16)
#define LSTRV 136  // Vs row stride (u16): 128 cols + 8 pad
#define LSTRP 68   // Ps row stride (u16): 64 cols + 4 pad
#define SM_C 0.18033688011112043f  /* 0.125 * log2(e) */

__global__ __launch_bounds__(256, 2) void attn_kernel(
    const u16* __restrict__ q, const u16* __restrict__ k,
    const u16* __restrict__ vT, const int* __restrict__ mask,
    u16* __restrict__ ctx) {
  __shared__ __align__(16) u16 Ks[KVB * LSTR];       // 18432 B
  __shared__ __align__(16) u16 Vs[64 * LSTRV];       // 17408 B
  __shared__ __align__(16) u16 Ps[4][32 * LSTRP];    // 17408 B
  __shared__ __align__(16) float Msf[KVB];           // 512 B

  const int tid = threadIdx.x, lane = tid & 63, wv = tid >> 6;
  const int bh = blockIdx.y, b = bh >> 4, h = bh & 15;
  const int q0 = blockIdx.x * 128 + wv * 32;
  const u16* qb = q + (long)bh * SQ * DH;
  const u16* kb = k + (long)bh * SQ * DH;
  const u16* vb = vT + (long)bh * DH * SQ;
  const int g1 = lane >> 4;           // 0..3
  const int rq = lane & 15;
  const int rk = 8 * g1;
  const int r0 = 4 * g1;

  // Q fragments (B-operand)
  short8 aq[2][2];
#pragma unroll
  for (int m = 0; m < 2; ++m)
#pragma unroll
    for (int ks = 0; ks < 2; ++ks)
      aq[m][ks] = *(const short8*)&qb[(long)(q0 + m * 16 + rq) * DH + ks * 32 + rk];

  f32x4 oacc[2][4];
  float mrow[2], lrow[2];
#pragma unroll
  for (int m = 0; m < 2; ++m) {
    mrow[m] = -1.0e9f;
    lrow[m] = 0.f;
#pragma unroll
    for (int nf = 0; nf < 4; ++nf)
#pragma unroll
      for (int r = 0; r < 4; ++r) oacc[m][nf][r] = 0.f;
  }

  const int stg_r = tid >> 3;          // 0..31 (K rows)
  const int stg_c = (tid & 7) * 8;     // 0..56 (K cols)
  const int vr = tid >> 4;             // 0..15 (V rows)
  const int vc = (tid & 15) * 8;       // 0..120 (V cols)

  for (int t0 = 0; t0 < SQ; t0 += KVB) {
    // global -> regs (issue before barrier; latency overlaps prior tile tail)
    short8 kvr[4], vvr[4];
#pragma unroll
    for (int j = 0; j < 4; ++j)
      kvr[j] = *(const short8*)&kb[(long)(t0 + stg_r + 32 * j) * DH + stg_c];
#pragma unroll
    for (int j = 0; j < 4; ++j)
      vvr[j] = *(const short8*)&vb[(long)(vr + 16 * j) * SQ + t0 + vc];
    float mv = 0.f;
    if (tid < KVB) mv = (mask[b * SQ + t0 + tid] != 0) ? 0.f : -1.0e9f;

    __syncthreads();  // prior tile's LDS reads complete before overwrite
#pragma unroll
    for (int j = 0; j < 4; ++j)
      *(short8*)&Ks[(stg_r + 32 * j) * LSTR + stg_c] = kvr[j];
#pragma unroll
    for (int j = 0; j < 4; ++j)
      *(short8*)&Vs[(vr + 16 * j) * LSTRV + vc] = vvr[j];
    if (tid < KVB) Msf[tid] = mv;
    __syncthreads();  // staging visible

    // ---- S^T = K Q^T : sacc[m][f], lane q-col = rq, kv = f*16+4g1+r ----
    f32x4 sacc[2][8];
#pragma unroll
    for (int f = 0; f < 8; ++f) {
      const short8 k0 = *(const short8*)&Ks[(f * 16 + rq) * LSTR + rk];
      const short8 k1 = *(const short8*)&Ks[(f * 16 + rq) * LSTR + 32 + rk];
      f32x4 z;
#pragma unroll
      for (int r = 0; r < 4; ++r) z[r] = 0.f;
#pragma unroll
      for (int m = 0; m < 2; ++m) {
        f32x4 t = MFMA(k0, aq[m][0], z);
        sacc[m][f] = MFMA(k1, aq[m][1], t);
      }
    }

    // fused mask + scale + log2e (1 fma per score)
#pragma unroll
    for (int f = 0; f < 8; ++f) {
      const f32x4 mo = *(const f32x4*)&Msf[f * 16 + 4 * g1];
#pragma unroll
      for (int m = 0; m < 2; ++m)
#pragma unroll
        for (int r = 0; r < 4; ++r)
          sacc[m][f][r] = __builtin_fmaf(sacc[m][f][r], SM_C, mo[r]);
    }

    // ---- online softmax (log2 domain) ----
#pragma unroll
    for (int m = 0; m < 2; ++m) {
      f32x4 t4 = sacc[m][0];
#pragma unroll
      for (int f = 1; f < 8; ++f)
#pragma unroll
        for (int r = 0; r < 4; ++r) t4[r] = fmaxf(t4[r], sacc[m][f][r]);
      float vmax = fmaxf(fmaxf(t4[0], t4[1]), fmaxf(t4[2], t4[3]));
      vmax = fmaxf(vmax, __shfl_xor(vmax, 16));
      vmax = fmaxf(vmax, __shfl_xor(vmax, 32));

      const float mnew = fmaxf(mrow[m], vmax);
      const float sc = EXP2(mrow[m] - mnew);
      mrow[m] = mnew;

#pragma unroll
      for (int f = 0; f < 8; ++f)
#pragma unroll
        for (int r = 0; r < 4; ++r)
          sacc[m][f][r] = EXP2(sacc[m][f][r] - mnew);
      f32x4 s4;
#pragma unroll
      for (int r = 0; r < 4; ++r)
        s4[r] = ((sacc[m][0][r] + sacc[m][1][r]) + (sacc[m][2][r] + sacc[m][3][r])) +
                ((sacc[m][4][r] + sacc[m][5][r]) + (sacc[m][6][r] + sacc[m][7][r]));
      float tsum = (s4[0] + s4[1]) + (s4[2] + s4[3]);
      tsum += __shfl_xor(tsum, 16);
      tsum += __shfl_xor(tsum, 32);
      lrow[m] = lrow[m] * sc + tsum;

      // redistribute rescale to accumulator rows (q = m*16 + 4g1 + r)
      f32x4 scr;
#pragma unroll
      for (int r = 0; r < 4; ++r) scr[r] = __shfl(sc, 4 * g1 + r);
#pragma unroll
      for (int nf = 0; nf < 4; ++nf)
#pragma unroll
        for (int r = 0; r < 4; ++r) oacc[m][nf][r] *= scr[r];
    }

    // ---- PV in two 64-kv passes over one wave-private Ps buffer ----
#pragma unroll
    for (int half = 0; half < 2; ++half) {
      // P -> LDS (kv 64*half .. +63)
#pragma unroll
      for (int m = 0; m < 2; ++m)
#pragma unroll
        for (int fl = 0; fl < 4; ++fl) {
          const int f = half * 4 + fl;
          u32x2 w;
          w[0] = CVTPK(sacc[m][f][0], sacc[m][f][1]);
          w[1] = CVTPK(sacc[m][f][2], sacc[m][f][3]);
          *(u32x2*)&Ps[wv][(m * 16 + rq) * LSTRP + fl * 16 + 4 * g1] = w;
        }
      // O += P V  (wave-private: in-wave DS ordering, no barrier)
#pragma unroll
      for (int k2 = 0; k2 < 2; ++k2) {
        const int ks2 = half * 2 + k2;
        short8 pa[2];
#pragma unroll
        for (int m = 0; m < 2; ++m)
          pa[m] = *(const short8*)&Ps[wv][(m * 16 + rq) * LSTRP + k2 * 32 + rk];
#pragma unroll
        for (int nf = 0; nf < 4; ++nf) {
          const short8 bvv = *(const short8*)&Vs[(nf * 16 + rq) * LSTRV + ks2 * 32 + rk];
#pragma unroll
          for (int m = 0; m < 2; ++m)
            oacc[m][nf] = MFMA(pa[m], bvv, oacc[m][nf]);
        }
      }
    }
  }

  // epilogue: ctx[b][s][h][dh]
#pragma unroll
  for (int m = 0; m < 2; ++m) {
    const float inv = 1.0f / lrow[m];
    f32x4 invr;
#pragma unroll
    for (int r = 0; r < 4; ++r) invr[r] = __shfl(inv, 4 * g1 + r);
#pragma unroll
    for (int nf = 0; nf < 4; ++nf)
#pragma unroll
      for (int r = 0; r < 4; ++r) {
        const int s = q0 + m * 16 + r0 + r;
        const int dh = nf * 16 + rq;
        ctx[(((long)(b * SQ + s)) * NH + h) * DH + dh] = f2bf(oacc[m][nf][r] * invr[r]);
      }
  }
}

// =====================================================================
extern "C" void kernel_launch(void* const* d_in, const int* in_sizes, int n_in,
                              void* d_out, int out_size, void* d_ws, size_t ws_size,
                              hipStream_t stream) {
  const void* query = d_in[0];
  const int* mask = (const int*)d_in[1];
  const void* Wq = d_in[2];
  const void* bq = d_in[3];
  const void* Wk = d_in[4];
  const void* bk = d_in[5];
  const void* Wv = d_in[6];
  const void* bv = d_in[7];
  const void* Wo = d_in[8];
  const void* bo = d_in[9];

  // ws layout
  char* w = (char*)d_ws;
  int* flag = (int*)w;
  u16* qc = (u16*)(w + 256);                 // 8.39M u16
  u16* Wc = qc + (long)8388608;              // 4 x 1M u16  [Wq|Wk|Wv|Wo]
  u16* bc = Wc + (long)4 * 1048576;          // 4 x 1024 u16
  u16* qh = bc + 4096;                       // heads Q
  u16* kh = qh + (long)8388608;              // heads K
  u16* vT = kh + (long)8388608;              // V transposed
  u16* ctx = vT + (long)8388608;             // attention output

  dim3 blk(256);

  detect_dtype<<<1, 256, 0, stream>>>((const u16*)query, flag);
  cvt_tensor<<<2048, 256, 0, stream>>>(query, qc, 8388608 / 8, flag);
  cvt_w4<<<2048, 256, 0, stream>>>(Wq, Wk, Wv, Wo, Wc, flag);
  cvt_b4<<<2, 256, 0, stream>>>(bq, bk, bv, bo, bc, flag);

  const int M = 4 * SQ;  // 8192

  // fused QKV projection: 64 x 24 tiles
  gemm_qkv<<<dim3(1536), blk, 0, stream>>>(qc, Wc, bc, qh, kh, vT);

  dim3 attn_grid(SQ / 128, 64);
  attn_kernel<<<attn_grid, blk, 0, stream>>>(qh, kh, vT, mask, ctx);

  gemm_out<<<dim3((M / 128) * (DMODEL / 128)), blk, 0, stream>>>(
      ctx, Wc + 3 * 1048576, bc + 3072, d_out, flag, M, DMODEL, DMODEL);
}

// Round 9
// 332.950 us; speedup vs baseline: 1.0495x; 1.0495x over previous
//
#include <hip/hip_runtime.h>

typedef unsigned short u16;
typedef unsigned int u32;
typedef __attribute__((ext_vector_type(8))) short short8;
typedef __attribute__((ext_vector_type(8))) __bf16 bf16x8;
typedef __attribute__((ext_vector_type(4))) float f32x4;
typedef __attribute__((ext_vector_type(2))) u32 u32x2;

// ---------- bf16 <-> f32 (raw, RNE) ----------
__device__ __forceinline__ float bf2f(u16 u) { return __uint_as_float(((u32)u) << 16); }
__device__ __forceinline__ u16 f2bf(float f) {
  u32 u = __float_as_uint(f);
  u = (u + 0x7fffu + ((u >> 16) & 1u)) >> 16;
  return (u16)u;
}

// ---------- fast 2^x ----------
__device__ __forceinline__ float EXP2(float x) {
#if __has_builtin(__builtin_amdgcn_exp2f)
  return __builtin_amdgcn_exp2f(x);
#else
  return exp2f(x);
#endif
}

// ---------- packed f32x2 -> bf16x2 (RNE), gfx950 ----------
__device__ __forceinline__ u32 CVTPK(float lo, float hi) {
  u32 r;
  asm("v_cvt_pk_bf16_f32 %0, %1, %2" : "=v"(r) : "v"(lo), "v"(hi));
  return r;
}

__device__ __forceinline__ short8 mk_s8(u32 a, u32 b, u32 c, u32 d) {
  union { short8 s; u32 w[4]; } u;
  u.w[0] = a; u.w[1] = b; u.w[2] = c; u.w[3] = d;
  return u.s;
}

// ---------- MFMA wrapper ----------
template <typename V>
__device__ __forceinline__ auto mfma_try(V a, V b, f32x4 c, int)
    -> decltype(__builtin_amdgcn_mfma_f32_16x16x32_bf16(a, b, c, 0, 0, 0)) {
  return __builtin_amdgcn_mfma_f32_16x16x32_bf16(a, b, c, 0, 0, 0);
}
template <typename V>
__device__ __forceinline__ f32x4 mfma_try(V a, V b, f32x4 c, long) {
  return __builtin_amdgcn_mfma_f32_16x16x32_bf16(
      __builtin_bit_cast(bf16x8, a), __builtin_bit_cast(bf16x8, b), c, 0, 0, 0);
}
__device__ __forceinline__ f32x4 MFMA(short8 a, short8 b, f32x4 c) {
  return mfma_try(a, b, c, 0);
}

// ---------- async global->LDS, 16B per lane (GEMM only) ----------
#define GLOAD16(gsrc, ldst)                                                  \
  __builtin_amdgcn_global_load_lds(                                          \
      (const __attribute__((address_space(1))) void*)(gsrc),                 \
      (__attribute__((address_space(3))) void*)(ldst), 16, 0, 0)

// Problem constants
#define SQ 2048
#define NH 16
#define DH 64
#define DMODEL 1024

// =====================================================================
// dtype detector: flag=1 if inputs are float32, 0 if bf16.
// =====================================================================
__global__ void detect_dtype(const u16* __restrict__ q, int* __restrict__ flag) {
  __shared__ int cnt;
  if (threadIdx.x == 0) cnt = 0;
  __syncthreads();
  const int k = threadIdx.x * 16384 + 128;
  const u16 u = q[2 * k];
  const int e = (u >> 7) & 0xFF;
  if (e >= 96 && e <= 143) atomicAdd(&cnt, 1);
  __syncthreads();
  if (threadIdx.x == 0) *flag = (cnt < 128) ? 1 : 0;
}

// ---------- conversion helpers ----------
__device__ __forceinline__ short8 cvt8_f32(const float* s) {
  f32x4 a = *(const f32x4*)s;
  f32x4 b = *(const f32x4*)(s + 4);
  short8 o;
#pragma unroll
  for (int j = 0; j < 4; ++j) o[j] = (short)f2bf(a[j]);
#pragma unroll
  for (int j = 0; j < 4; ++j) o[4 + j] = (short)f2bf(b[j]);
  return o;
}

__global__ void cvt_tensor(const void* __restrict__ src, u16* __restrict__ dst,
                           int n8, const int* __restrict__ flag) {
  const bool isf32 = (*flag != 0);
  int i = blockIdx.x * blockDim.x + threadIdx.x;
  const int stride = gridDim.x * blockDim.x;
  if (isf32) {
    const float* s = (const float*)src;
    for (; i < n8; i += stride) *(short8*)(dst + i * 8) = cvt8_f32(s + i * 8);
  } else {
    const short8* s = (const short8*)src;
    for (; i < n8; i += stride) *(short8*)(dst + i * 8) = s[i];
  }
}

__global__ void cvt_w4(const void* s0, const void* s1, const void* s2, const void* s3,
                       u16* __restrict__ dst, const int* __restrict__ flag) {
  const bool isf32 = (*flag != 0);
  int i = blockIdx.x * blockDim.x + threadIdx.x;
  const int stride = gridDim.x * blockDim.x;
  for (; i < (1 << 19); i += stride) {
    const int seg = i >> 17, off = i & ((1 << 17) - 1);
    const void* s = (seg == 0) ? s0 : (seg == 1) ? s1 : (seg == 2) ? s2 : s3;
    u16* d = dst + ((long)seg << 20) + (long)off * 8;
    if (isf32) *(short8*)d = cvt8_f32((const float*)s + off * 8);
    else *(short8*)d = *((const short8*)s + off);
  }
}

__global__ void cvt_b4(const void* s0, const void* s1, const void* s2, const void* s3,
                       u16* __restrict__ dst, const int* __restrict__ flag) {
  const bool isf32 = (*flag != 0);
  int i = blockIdx.x * blockDim.x + threadIdx.x;
  if (i >= 512) return;
  const int seg = i >> 7, off = i & 127;
  const void* s = (seg == 0) ? s0 : (seg == 1) ? s1 : (seg == 2) ? s2 : s3;
  u16* d = dst + seg * 1024 + off * 8;
  if (isf32) *(short8*)d = cvt8_f32((const float*)s + off * 8);
  else *(short8*)d = *((const short8*)s + off);
}

// =====================================================================
// Fused QKV GEMM: A[8192][1024] x W[3072][1024]^T + bias[3072]
// XCD-L2-blocked mapping: each XCD owns 8 tm rows; within, 3 sub-slabs
// of 8tm x 8tn (resident set = 2MB A + 2MB B = one XCD L2).
// =====================================================================
__global__ __launch_bounds__(256, 2) void gemm_qkv(
    const u16* __restrict__ A, const u16* __restrict__ W,
    const u16* __restrict__ bias, u16* __restrict__ qb,
    u16* __restrict__ kb, u16* __restrict__ vT) {
  __shared__ __align__(16) u16 As[128 * 32];
  __shared__ __align__(16) u16 Bs[128 * 32];
  const int tid = threadIdx.x;
  const int lane = tid & 63;
  const int wv = tid >> 6;
  const int wr = wv >> 1, wc = wv & 1;
  const int K = DMODEL;

  // XCD chunk + 8x8 sub-slab blocking (bijective, 1536 = 8 x 3 x 64)
  const int x = blockIdx.x & 7;          // XCD
  const int local = blockIdx.x >> 3;     // 0..191
  const int sub = local >> 6;            // 0..2
  const int within = local & 63;         // 0..63
  const int tm = x * 8 + (within >> 3);  // 0..63
  const int tn = sub * 8 + (within & 7); // 0..23
  const int m0 = tm << 7, n0 = tn << 7;

  f32x4 acc[4][4];
#pragma unroll
  for (int i = 0; i < 4; ++i)
#pragma unroll
    for (int j = 0; j < 4; ++j)
#pragma unroll
      for (int r = 0; r < 4; ++r) acc[i][j][r] = 0.f;

  const int srow = tid >> 2;
  const int skk = (tid & 3) * 8;
  const u16* a0 = A + (long)(m0 + srow) * K + skk;
  const u16* a1 = A + (long)(m0 + 64 + srow) * K + skk;
  const u16* b0 = W + (long)(n0 + srow) * K + skk;
  const u16* b1 = W + (long)(n0 + 64 + srow) * K + skk;
  u16* lA0 = &As[tid * 8];
  u16* lA1 = &As[(256 + tid) * 8];
  u16* lB0 = &Bs[tid * 8];
  u16* lB1 = &Bs[(256 + tid) * 8];

  const int rk = 8 * (lane >> 4);
  const int rrow = lane & 15;
  const int r0 = (lane >> 4) * 4;

  for (int k0 = 0; k0 < K; k0 += 32) {
    GLOAD16(a0 + k0, lA0);
    GLOAD16(a1 + k0, lA1);
    GLOAD16(b0 + k0, lB0);
    GLOAD16(b1 + k0, lB1);
    asm volatile("s_waitcnt vmcnt(0)" ::: "memory");
    __syncthreads();
    short8 af[4], bf[4];
#pragma unroll
    for (int mi = 0; mi < 4; ++mi)
      af[mi] = *(const short8*)&As[(wr * 64 + mi * 16 + rrow) * 32 + rk];
#pragma unroll
    for (int ni = 0; ni < 4; ++ni)
      bf[ni] = *(const short8*)&Bs[(wc * 64 + ni * 16 + rrow) * 32 + rk];
#pragma unroll
    for (int mi = 0; mi < 4; ++mi)
#pragma unroll
      for (int ni = 0; ni < 4; ++ni)
        acc[mi][ni] = MFMA(af[mi], bf[ni], acc[mi][ni]);
    __syncthreads();
  }

  // epilogue with block-uniform segment routing
  const int seg = n0 >> 10;             // 0=Q, 1=K, 2=V
  const int nbase = n0 & 1023;
  u16* dst = (seg == 0) ? qb : (seg == 1) ? kb : vT;
#pragma unroll
  for (int ni = 0; ni < 4; ++ni) {
    const int col = n0 + wc * 64 + ni * 16 + rrow;
    const float bv = bf2f(bias[col]);
    const int cl = nbase + wc * 64 + ni * 16 + rrow;
    const int h = cl >> 6, dh = cl & 63;
#pragma unroll
    for (int mi = 0; mi < 4; ++mi) {
#pragma unroll
      for (int r = 0; r < 4; ++r) {
        const int row = m0 + wr * 64 + mi * 16 + r0 + r;
        const float v = acc[mi][ni][r] + bv;
        const int b = row >> 11, s = row & 2047;
        if (seg < 2) {
          dst[(((long)(b * NH + h) * SQ) + s) * DH + dh] = f2bf(v);
        } else {
          dst[(((long)(b * NH + h) * DH) + dh) * SQ + s] = f2bf(v);
        }
      }
    }
  }
}

// =====================================================================
// Wo GEMM: C[M][N] = A[M][K] * W[N][K]^T + bias[N], row-major out
// =====================================================================
__global__ __launch_bounds__(256, 2) void gemm_out(
    const u16* __restrict__ A, const u16* __restrict__ W,
    const u16* __restrict__ bias, void* __restrict__ Cv,
    const int* __restrict__ flag, int M, int N, int K) {
  __shared__ __align__(16) u16 As[128 * 32];
  __shared__ __align__(16) u16 Bs[128 * 32];
  const int tid = threadIdx.x;
  const int lane = tid & 63;
  const int wv = tid >> 6;
  const int wr = wv >> 1, wc = wv & 1;
  const bool isf32 = (*flag != 0);

  const int nwg = gridDim.x;
  const int cpx = nwg >> 3;
  const int bid = (blockIdx.x % 8) * cpx + (blockIdx.x >> 3);

  const int tiles_n = N >> 7;
  const int tm = bid / tiles_n, tn = bid % tiles_n;
  const int m0 = tm << 7, n0 = tn << 7;

  f32x4 acc[4][4];
#pragma unroll
  for (int i = 0; i < 4; ++i)
#pragma unroll
    for (int j = 0; j < 4; ++j)
#pragma unroll
      for (int r = 0; r < 4; ++r) acc[i][j][r] = 0.f;

  const int srow = tid >> 2;
  const int skk = (tid & 3) * 8;
  const u16* a0 = A + (long)(m0 + srow) * K + skk;
  const u16* a1 = A + (long)(m0 + 64 + srow) * K + skk;
  const u16* b0 = W + (long)(n0 + srow) * K + skk;
  const u16* b1 = W + (long)(n0 + 64 + srow) * K + skk;
  u16* lA0 = &As[tid * 8];
  u16* lA1 = &As[(256 + tid) * 8];
  u16* lB0 = &Bs[tid * 8];
  u16* lB1 = &Bs[(256 + tid) * 8];

  const int rk = 8 * (lane >> 4);
  const int rrow = lane & 15;
  const int r0 = (lane >> 4) * 4;

  for (int k0 = 0; k0 < K; k0 += 32) {
    GLOAD16(a0 + k0, lA0);
    GLOAD16(a1 + k0, lA1);
    GLOAD16(b0 + k0, lB0);
    GLOAD16(b1 + k0, lB1);
    asm volatile("s_waitcnt vmcnt(0)" ::: "memory");
    __syncthreads();
    short8 af[4], bf[4];
#pragma unroll
    for (int mi = 0; mi < 4; ++mi)
      af[mi] = *(const short8*)&As[(wr * 64 + mi * 16 + rrow) * 32 + rk];
#pragma unroll
    for (int ni = 0; ni < 4; ++ni)
      bf[ni] = *(const short8*)&Bs[(wc * 64 + ni * 16 + rrow) * 32 + rk];
#pragma unroll
    for (int mi = 0; mi < 4; ++mi)
#pragma unroll
      for (int ni = 0; ni < 4; ++ni)
        acc[mi][ni] = MFMA(af[mi], bf[ni], acc[mi][ni]);
    __syncthreads();
  }

#pragma unroll
  for (int ni = 0; ni < 4; ++ni) {
    const int col = n0 + wc * 64 + ni * 16 + rrow;
    const float bv = bf2f(bias[col]);
#pragma unroll
    for (int mi = 0; mi < 4; ++mi) {
#pragma unroll
      for (int r = 0; r < 4; ++r) {
        const int row = m0 + wr * 64 + mi * 16 + r0 + r;
        const float v = acc[mi][ni][r] + bv;
        const long idx = (long)row * N + col;
        if (isf32) ((float*)Cv)[idx] = v;
        else ((u16*)Cv)[idx] = f2bf(v);
      }
    }
  }
}

// =====================================================================
// Flash attention, swapped-QK^T, KVBLK=128, zero-cross-lane P.
// P stays in registers: with PV contraction order kv(k)=32ks2+16j+4g1+r,
// the A-fragment value at k=8g1+4j+r is exactly sacc[m][2ks2+j][r] (lane-
// local). V B-fragments read as two ds_read_b64 at kv +0/+16.
// 1-D grid 1024, XCD-chunked: xcd owns 8 heads x 16 q-tiles (K/V in L2).
// =====================================================================
#define KVB 128
#define LSTR 72    // Ks row stride (u16)
#define LSTRV 136  // Vs row stride (u16)
#define SM_C 0.18033688011112043f  /* 0.125 * log2(e) */

__global__ __launch_bounds__(256, 3) void attn_kernel(
    const u16* __restrict__ q, const u16* __restrict__ k,
    const u16* __restrict__ vT, const int* __restrict__ mask,
    u16* __restrict__ ctx) {
  __shared__ __align__(16) u16 Ks[KVB * LSTR];       // 18432 B
  __shared__ __align__(16) u16 Vs[64 * LSTRV];       // 17408 B
  __shared__ __align__(16) float Msf[KVB];           // 512 B

  const int tid = threadIdx.x, lane = tid & 63, wv = tid >> 6;
  // XCD-aware decomposition: xcd = blk&7 owns heads [xcd*8, xcd*8+8)
  const int xcd = blockIdx.x & 7;
  const int local = blockIdx.x >> 3;      // 0..127
  const int bh = xcd * 8 + (local >> 4);  // 0..63
  const int qt = local & 15;              // q-tile 0..15
  const int b = bh >> 4, h = bh & 15;
  const int q0 = qt * 128 + wv * 32;
  const u16* qb = q + (long)bh * SQ * DH;
  const u16* kb = k + (long)bh * SQ * DH;
  const u16* vb = vT + (long)bh * DH * SQ;
  const int g1 = lane >> 4;           // 0..3
  const int rq = lane & 15;
  const int rk = 8 * g1;
  const int r0 = 4 * g1;

  // Q fragments (B-operand)
  short8 aq[2][2];
#pragma unroll
  for (int m = 0; m < 2; ++m)
#pragma unroll
    for (int ks = 0; ks < 2; ++ks)
      aq[m][ks] = *(const short8*)&qb[(long)(q0 + m * 16 + rq) * DH + ks * 32 + rk];

  f32x4 oacc[2][4];
  float mrow[2], lrow[2];
#pragma unroll
  for (int m = 0; m < 2; ++m) {
    mrow[m] = -1.0e9f;
    lrow[m] = 0.f;
#pragma unroll
    for (int nf = 0; nf < 4; ++nf)
#pragma unroll
      for (int r = 0; r < 4; ++r) oacc[m][nf][r] = 0.f;
  }

  const int stg_r = tid >> 3;          // 0..31 (K rows)
  const int stg_c = (tid & 7) * 8;     // 0..56 (K cols)
  const int vr = tid >> 4;             // 0..15 (V rows)
  const int vc = (tid & 15) * 8;       // 0..120 (V cols)

  for (int t0 = 0; t0 < SQ; t0 += KVB) {
    // global -> regs
    short8 kvr[4], vvr[4];
#pragma unroll
    for (int j = 0; j < 4; ++j)
      kvr[j] = *(const short8*)&kb[(long)(t0 + stg_r + 32 * j) * DH + stg_c];
#pragma unroll
    for (int j = 0; j < 4; ++j)
      vvr[j] = *(const short8*)&vb[(long)(vr + 16 * j) * SQ + t0 + vc];
    float mv = 0.f;
    if (tid < KVB) mv = (mask[b * SQ + t0 + tid] != 0) ? 0.f : -1.0e9f;

    __syncthreads();  // prior tile's LDS reads complete before overwrite
#pragma unroll
    for (int j = 0; j < 4; ++j)
      *(short8*)&Ks[(stg_r + 32 * j) * LSTR + stg_c] = kvr[j];
#pragma unroll
    for (int j = 0; j < 4; ++j)
      *(short8*)&Vs[(vr + 16 * j) * LSTRV + vc] = vvr[j];
    if (tid < KVB) Msf[tid] = mv;
    __syncthreads();  // staging visible

    // ---- S^T = K Q^T : sacc[m][f], lane q-col = rq, kv = f*16+4g1+r ----
    f32x4 sacc[2][8];
#pragma unroll
    for (int f = 0; f < 8; ++f) {
      const short8 k0 = *(const short8*)&Ks[(f * 16 + rq) * LSTR + rk];
      const short8 k1 = *(const short8*)&Ks[(f * 16 + rq) * LSTR + 32 + rk];
      f32x4 z;
#pragma unroll
      for (int r = 0; r < 4; ++r) z[r] = 0.f;
#pragma unroll
      for (int m = 0; m < 2; ++m) {
        f32x4 t = MFMA(k0, aq[m][0], z);
        sacc[m][f] = MFMA(k1, aq[m][1], t);
      }
    }

    // fused mask + scale + log2e (1 fma per score)
#pragma unroll
    for (int f = 0; f < 8; ++f) {
      const f32x4 mo = *(const f32x4*)&Msf[f * 16 + 4 * g1];
#pragma unroll
      for (int m = 0; m < 2; ++m)
#pragma unroll
        for (int r = 0; r < 4; ++r)
          sacc[m][f][r] = __builtin_fmaf(sacc[m][f][r], SM_C, mo[r]);
    }

    // ---- online softmax (log2 domain) + in-register P packing ----
    short8 pa[2][4];
#pragma unroll
    for (int m = 0; m < 2; ++m) {
      f32x4 t4 = sacc[m][0];
#pragma unroll
      for (int f = 1; f < 8; ++f)
#pragma unroll
        for (int r = 0; r < 4; ++r) t4[r] = fmaxf(t4[r], sacc[m][f][r]);
      float vmax = fmaxf(fmaxf(t4[0], t4[1]), fmaxf(t4[2], t4[3]));
      vmax = fmaxf(vmax, __shfl_xor(vmax, 16));
      vmax = fmaxf(vmax, __shfl_xor(vmax, 32));

      const float mnew = fmaxf(mrow[m], vmax);
      const float sc = EXP2(mrow[m] - mnew);
      mrow[m] = mnew;

#pragma unroll
      for (int f = 0; f < 8; ++f)
#pragma unroll
        for (int r = 0; r < 4; ++r)
          sacc[m][f][r] = EXP2(sacc[m][f][r] - mnew);
      f32x4 s4;
#pragma unroll
      for (int r = 0; r < 4; ++r)
        s4[r] = ((sacc[m][0][r] + sacc[m][1][r]) + (sacc[m][2][r] + sacc[m][3][r])) +
                ((sacc[m][4][r] + sacc[m][5][r]) + (sacc[m][6][r] + sacc[m][7][r]));
      float tsum = (s4[0] + s4[1]) + (s4[2] + s4[3]);
      tsum += __shfl_xor(tsum, 16);
      tsum += __shfl_xor(tsum, 32);
      lrow[m] = lrow[m] * sc + tsum;

      // redistribute rescale to accumulator rows (q = m*16 + 4g1 + r)
      f32x4 scr;
#pragma unroll
      for (int r = 0; r < 4; ++r) scr[r] = __shfl(sc, 4 * g1 + r);
#pragma unroll
      for (int nf = 0; nf < 4; ++nf)
#pragma unroll
        for (int r = 0; r < 4; ++r) oacc[m][nf][r] *= scr[r];

      // pack P -> A-fragments in-register (zero cross-lane):
      // pa[m][ks2] element 4j+r  =  P[kv=32ks2+16j+4g1+r][q=rq] = sacc[m][2ks2+j][r]
#pragma unroll
      for (int ks2 = 0; ks2 < 4; ++ks2)
        pa[m][ks2] = mk_s8(CVTPK(sacc[m][2 * ks2][0], sacc[m][2 * ks2][1]),
                           CVTPK(sacc[m][2 * ks2][2], sacc[m][2 * ks2][3]),
                           CVTPK(sacc[m][2 * ks2 + 1][0], sacc[m][2 * ks2 + 1][1]),
                           CVTPK(sacc[m][2 * ks2 + 1][2], sacc[m][2 * ks2 + 1][3]));
    }

    // ---- O += P V : B-fragment k=8g1+4j+r reads V^T[dh][32ks2+16j+4g1+r] ----
#pragma unroll
    for (int ks2 = 0; ks2 < 4; ++ks2) {
#pragma unroll
      for (int nf = 0; nf < 4; ++nf) {
        const int base = (nf * 16 + rq) * LSTRV + ks2 * 32 + 4 * g1;
        const u32x2 lo = *(const u32x2*)&Vs[base];
        const u32x2 hi = *(const u32x2*)&Vs[base + 16];
        const short8 bvv = mk_s8(lo[0], lo[1], hi[0], hi[1]);
#pragma unroll
        for (int m = 0; m < 2; ++m)
          oacc[m][nf] = MFMA(pa[m][ks2], bvv, oacc[m][nf]);
      }
    }
  }

  // epilogue: ctx[b][s][h][dh]
#pragma unroll
  for (int m = 0; m < 2; ++m) {
    const float inv = 1.0f / lrow[m];
    f32x4 invr;
#pragma unroll
    for (int r = 0; r < 4; ++r) invr[r] = __shfl(inv, 4 * g1 + r);
#pragma unroll
    for (int nf = 0; nf < 4; ++nf)
#pragma unroll
      for (int r = 0; r < 4; ++r) {
        const int s = q0 + m * 16 + r0 + r;
        const int dh = nf * 16 + rq;
        ctx[(((long)(b * SQ + s)) * NH + h) * DH + dh] = f2bf(oacc[m][nf][r] * invr[r]);
      }
  }
}

// =====================================================================
extern "C" void kernel_launch(void* const* d_in, const int* in_sizes, int n_in,
                              void* d_out, int out_size, void* d_ws, size_t ws_size,
                              hipStream_t stream) {
  const void* query = d_in[0];
  const int* mask = (const int*)d_in[1];
  const void* Wq = d_in[2];
  const void* bq = d_in[3];
  const void* Wk = d_in[4];
  const void* bk = d_in[5];
  const void* Wv = d_in[6];
  const void* bv = d_in[7];
  const void* Wo = d_in[8];
  const void* bo = d_in[9];

  // ws layout
  char* w = (char*)d_ws;
  int* flag = (int*)w;
  u16* qc = (u16*)(w + 256);                 // 8.39M u16
  u16* Wc = qc + (long)8388608;              // 4 x 1M u16  [Wq|Wk|Wv|Wo]
  u16* bc = Wc + (long)4 * 1048576;          // 4 x 1024 u16
  u16* qh = bc + 4096;                       // heads Q
  u16* kh = qh + (long)8388608;              // heads K
  u16* vT = kh + (long)8388608;              // V transposed
  u16* ctx = vT + (long)8388608;             // attention output

  dim3 blk(256);

  detect_dtype<<<1, 256, 0, stream>>>((const u16*)query, flag);
  cvt_tensor<<<2048, 256, 0, stream>>>(query, qc, 8388608 / 8, flag);
  cvt_w4<<<2048, 256, 0, stream>>>(Wq, Wk, Wv, Wo, Wc, flag);
  cvt_b4<<<2, 256, 0, stream>>>(bq, bk, bv, bo, bc, flag);

  const int M = 4 * SQ;  // 8192

  // fused QKV projection: 1536 blocks, XCD-L2-blocked
  gemm_qkv<<<dim3(1536), blk, 0, stream>>>(qc, Wc, bc, qh, kh, vT);

  // attention: 1024 blocks, XCD-chunked by head
  attn_kernel<<<dim3(1024), blk, 0, stream>>>(qh, kh, vT, mask, ctx);

  gemm_out<<<dim3((M / 128) * (DMODEL / 128)), blk, 0, stream>>>(
      ctx, Wc + 3 * 1048576, bc + 3072, d_out, flag, M, DMODEL, DMODEL);
}